// Round 6
// baseline (427.025 us; speedup 1.0000x reference)
//
#include <hip/hip_runtime.h>
#include <hip/hip_bf16.h>
#include <math.h>

// MultiHeadAttention: B=4, S=2048, D=1024, H=16, DK=64, fp32 in/out.
// Round 10:
//  - GEMMs: wave tile 128x64 (RM=8,RN=4), 8 waves -> 256x256 block. Raises
//    MFMA:ds_read ratio 3:1 -> 4:1 (LDS-BW cap 47% -> 62% MfmaUtil; round-9
//    counters showed LDS read BW is the binding limit). 2 LDS buffers
//    (128 KiB), distance-1 prefetch staged across phases 0-1, one vmcnt(0)
//    publish per chunk. Same 3-phase mid-barrier structure, same pass order
//    (hi*hi, lo*hi, hi*lo) -> bit-identical numerics.
//  - attention + fused split unchanged from round 9.

constexpr int D = 1024;
constexpr int H = 16;
constexpr int DK = 64;
constexpr int PSTR = 72;  // P row stride (u16)

typedef unsigned short u16;
typedef __attribute__((ext_vector_type(8))) short v8s;
typedef __attribute__((ext_vector_type(4))) float v4f;
typedef const __attribute__((address_space(1))) void gvoid;
typedef __attribute__((address_space(3))) void lvoid;
typedef __attribute__((address_space(3))) u16 ls_u16;
typedef __attribute__((address_space(3))) v8s lv8s;

__device__ __forceinline__ u16 rne_bf16(float f) {
  unsigned u = __float_as_uint(f);
  u += 0x7FFFu + ((u >> 16) & 1u);
  return (u16)(u >> 16);
}

__device__ __forceinline__ unsigned pk_bf16(float a, float b) {
  __hip_bfloat162 t = __float22bfloat162_rn(float2{a, b});
  return *reinterpret_cast<unsigned*>(&t);
}

__device__ __forceinline__ void cfence() { asm volatile("" ::: "memory"); }

// ---------------- fp32 -> bf16 hi/lo split ----------------
__device__ __forceinline__ void split_body(const float* __restrict__ in,
                                           u16* __restrict__ hi, u16* __restrict__ lo,
                                           int i)
{
  const float4 v = ((const float4*)in)[i];
  const float f[4] = {v.x, v.y, v.z, v.w};
  ushort4 h, l;
  u16 hh[4], ll[4];
#pragma unroll
  for (int j = 0; j < 4; ++j) {
    const unsigned u = __float_as_uint(f[j]);
    hh[j] = (u16)(u >> 16);
    const float hf = __uint_as_float(u & 0xFFFF0000u);
    ll[j] = rne_bf16(f[j] - hf);
  }
  h.x = hh[0]; h.y = hh[1]; h.z = hh[2]; h.w = hh[3];
  l.x = ll[0]; l.y = ll[1]; l.z = ll[2]; l.w = ll[3];
  ((ushort4*)hi)[i] = h;
  ((ushort4*)lo)[i] = l;
}

// one launch for ALL splits: linear float4 index space =
// [x: n4x) ++ [Wq,Wk,Wv: 3*N4W) ++ [Wo: N4W)
__global__ __launch_bounds__(256) void split_all_kernel(
    const float* __restrict__ x,
    const float* __restrict__ w0, const float* __restrict__ w1,
    const float* __restrict__ w2, const float* __restrict__ w3,
    u16* __restrict__ xs_hi, u16* __restrict__ xs_lo,
    u16* __restrict__ qkv_hi, u16* __restrict__ qkv_lo,
    u16* __restrict__ o_hi, u16* __restrict__ o_lo, int n4x)
{
  constexpr int N4W = (int)(D * (size_t)D / 4);  // 262144 (pow2)
  const int i = blockIdx.x * 256 + threadIdx.x;
  if (i < n4x) {
    split_body(x, xs_hi, xs_lo, i);
    return;
  }
  const int t = i - n4x;
  const int y = t / N4W;        // pow2 -> shift
  const int j = t - y * N4W;
  if (y >= 4) return;
  const float* src = (y == 0) ? w0 : (y == 1) ? w1 : (y == 2) ? w2 : w3;
  const size_t off = (size_t)y * (size_t)(D * (size_t)D);
  u16* hi = (y < 3) ? qkv_hi + off : o_hi;
  u16* lo = (y < 3) ? qkv_lo + off : o_lo;
  split_body(src, hi, lo, j);
}

// ---------------- staging: R rows x 32 cols u16, pre-swizzled source ----------
// LDS chunk c of row r holds global 16B-chunk c ^ ((r>>1)&3); LDS dest linear.
template<int R>
__device__ __forceinline__ void stage_arr(const u16* __restrict__ src, ls_u16* dst,
                                          int tid, int row0, int k0)
{
  const int cg = (tid & 3) ^ ((tid >> 3) & 3);
#pragma unroll
  for (int j = 0; j < R / 128; ++j) {
    const int row = j * 128 + (tid >> 2);
    __builtin_amdgcn_global_load_lds(
        (gvoid*)(src + (size_t)(row0 + row) * D + k0 + cg * 8),
        (lvoid*)(dst + j * 4096 + tid * 8), 16, 0, 0);
  }
}

// ---------------- deep-pipelined split-bf16 GEMM, 256x256 / 128x64-wave ------
// 512 threads = 8 waves (2m x 4n), wave tile 128x64 (RM=8, RN=4).
// 2 LDS buffers {Ahi|Alo|Bhi|Blo} (64 KiB each), distance-1 prefetch staged in
// phases 0-1, ONE vmcnt(0)+barrier publish per chunk; 2 mid-phase barriers.
// 3 MFMA passes per chunk: hi*hi, lo*hi, hi*lo (order == rounds 4-9).
// EPI=0: QKV epilogue (bf16 head-split Q/K natural, V transposed).
// EPI=1: fp32 natural + bias.
template<int EPI>
__global__ __launch_bounds__(512, 2) void gemm_pipe_kernel(
    const u16* __restrict__ Ahi, const u16* __restrict__ Alo,
    const u16* __restrict__ Whi, const u16* __restrict__ Wlo,
    const float* __restrict__ b0v, const float* __restrict__ b1v, const float* __restrict__ b2v,
    u16* __restrict__ Qb, u16* __restrict__ Kb, u16* __restrict__ Vtb,
    float* __restrict__ C, int S_)
{
  constexpr int BM = 256, BN = 256;
  constexpr int TA = BM * 32;            // 8192 u16 per A array tile
  constexpr int TB = BN * 32;            // 8192 u16 per B array tile
  constexpr int BUFSZ = 2 * TA + 2 * TB; // {Ahi, Alo, Bhi, Blo} = 64 KiB
  __shared__ u16 lds[2][BUFSZ];          // 128 KiB

  const int tid = threadIdx.x;
  const int lane = tid & 63, w = tid >> 6;
  const int wm = (w >> 2) * 128, wn = (w & 3) * 64;
  const int fr = lane & 15, fq = lane >> 4;
  const int csw = (fq ^ ((fr >> 1) & 3)) * 8;  // swizzled k-chunk (u16 units)

  // XCD-contiguous id, then grouped mapping (GM m-tiles x all n per group).
  const int gx = gridDim.x;   // m tiles (multiple of GM)
  const int gyd = gridDim.y;  // n tiles
  const int nwg = gx * gyd;   // multiple of 8
  int id = blockIdx.y * gx + blockIdx.x;
  id = (id & 7) * (nwg >> 3) + (id >> 3);
  constexpr int GM = 4;
  const int per_grp = GM * gyd;
  const int grp = id / per_grp;
  const int ing = id - grp * per_grp;
  const int m0 = (grp * GM + (ing & (GM - 1))) * BM;
  const int n0 = (ing / GM) * BN;

  v4f acc[8][4];
#pragma unroll
  for (int mi = 0; mi < 8; ++mi)
#pragma unroll
    for (int ni = 0; ni < 4; ++ni) acc[mi][ni] = (v4f){0.f, 0.f, 0.f, 0.f};

  ls_u16* pb0 = (ls_u16*)&lds[0][0];
  ls_u16* pb1 = (ls_u16*)&lds[1][0];

  int aoff[8], boff[4];
#pragma unroll
  for (int i = 0; i < 8; ++i) aoff[i] = (wm + i * 16 + fr) * 32 + csw;
#pragma unroll
  for (int i = 0; i < 4; ++i) boff[i] = 2 * TA + (wn + i * 16 + fr) * 32 + csw;

  // prologue: stage chunk 0 into pb0 (8 loads/thread)
  stage_arr<BM>(Ahi, pb0, tid, m0, 0);
  stage_arr<BM>(Alo, pb0 + TA, tid, m0, 0);
  stage_arr<BN>(Whi, pb0 + 2 * TA, tid, n0, 0);
  stage_arr<BN>(Wlo, pb0 + 2 * TA + TB, tid, n0, 0);
  asm volatile("s_waitcnt vmcnt(0)" ::: "memory");
  __builtin_amdgcn_s_barrier();
  cfence();

#pragma unroll 2
  for (int k = 0; k < 32; ++k) {
    // chunk k+1 into pb1 (held chunk k-1; all reads of it finished before the
    // publish barrier that ended iteration k-1). Clamped tail keeps vmcnt
    // bookkeeping uniform (re-stages chunk 31, never read).
    const int ks = (k + 1 < 32) ? (k + 1) * 32 : 31 * 32;

    // ===== phase 0: read ah,bh; stage next A hi/lo; MFMA hi*hi =====
    v8s ah[8], bh[4], tf[8];
#pragma unroll
    for (int i = 0; i < 8; ++i) ah[i] = *(const lv8s*)(pb0 + aoff[i]);
#pragma unroll
    for (int i = 0; i < 4; ++i) bh[i] = *(const lv8s*)(pb0 + boff[i]);
    stage_arr<BM>(Ahi, pb1, tid, m0, ks);       // 2 loads
    stage_arr<BM>(Alo, pb1 + TA, tid, m0, ks);  // 2 loads
    __builtin_amdgcn_s_setprio(1);
#pragma unroll
    for (int mi = 0; mi < 8; ++mi)
#pragma unroll
      for (int ni = 0; ni < 4; ++ni)
        acc[mi][ni] = __builtin_amdgcn_mfma_f32_16x16x32_bf16(ah[mi], bh[ni], acc[mi][ni], 0, 0, 0);
    __builtin_amdgcn_s_setprio(0);
    cfence();
    __builtin_amdgcn_s_barrier();
    cfence();

    // ===== phase 1: read al; stage next B hi/lo; MFMA lo*hi =====
#pragma unroll
    for (int i = 0; i < 8; ++i) tf[i] = *(const lv8s*)(pb0 + TA + aoff[i]);
    stage_arr<BN>(Whi, pb1 + 2 * TA, tid, n0, ks);       // 2 loads
    stage_arr<BN>(Wlo, pb1 + 2 * TA + TB, tid, n0, ks);  // 2 loads
    __builtin_amdgcn_s_setprio(1);
#pragma unroll
    for (int mi = 0; mi < 8; ++mi)
#pragma unroll
      for (int ni = 0; ni < 4; ++ni)
        acc[mi][ni] = __builtin_amdgcn_mfma_f32_16x16x32_bf16(tf[mi], bh[ni], acc[mi][ni], 0, 0, 0);
    __builtin_amdgcn_s_setprio(0);
    cfence();
    __builtin_amdgcn_s_barrier();
    cfence();

    // ===== phase 2: read bl; MFMA hi*lo =====
#pragma unroll
    for (int i = 0; i < 4; ++i) tf[i] = *(const lv8s*)(pb0 + boff[i] + TB);
    __builtin_amdgcn_s_setprio(1);
#pragma unroll
    for (int mi = 0; mi < 8; ++mi)
#pragma unroll
      for (int ni = 0; ni < 4; ++ni)
        acc[mi][ni] = __builtin_amdgcn_mfma_f32_16x16x32_bf16(ah[mi], tf[ni], acc[mi][ni], 0, 0, 0);
    __builtin_amdgcn_s_setprio(0);
    cfence();

    // publish: this chunk's 8 stage loads complete; all waves done with pb0.
    asm volatile("s_waitcnt vmcnt(0)" ::: "memory");
    __builtin_amdgcn_s_barrier();
    cfence();

    ls_u16* t = pb0; pb0 = pb1; pb1 = t;
  }

  const int lane4 = fq * 4;
  if constexpr (EPI == 0) {
    const int wsel = n0 >> 10;  // BN=256 block stays within one of Q/K/V
    const float* bias = (wsel == 0) ? b0v : (wsel == 1) ? b1v : b2v;
    u16* Cb = (wsel == 0) ? Qb : (wsel == 1) ? Kb : Vtb;
    const int bb = m0 / S_;     // block spans a single batch (S_ % BM == 0)
    const int s0 = m0 - bb * S_;
#pragma unroll
    for (int mi = 0; mi < 8; ++mi) {
#pragma unroll
      for (int ni = 0; ni < 4; ++ni) {
        const int n = n0 + wn + ni * 16 + fr;
        const int nl = n & (D - 1);
        const float bvv = bias[nl];
        const int h = nl >> 6, dk = nl & 63;
#pragma unroll
        for (int r = 0; r < 4; ++r) {
          const int s = s0 + wm + mi * 16 + lane4 + r;
          const float val = acc[mi][ni][r] + bvv;
          if (wsel < 2)
            Cb[((size_t)(bb * H + h) * S_ + s) * DK + dk] = rne_bf16(val);
          else
            Cb[((size_t)(bb * H + h) * DK + dk) * S_ + s] = rne_bf16(val);
        }
      }
    }
  } else {
#pragma unroll
    for (int mi = 0; mi < 8; ++mi)
#pragma unroll
      for (int ni = 0; ni < 4; ++ni) {
        const int n = n0 + wn + ni * 16 + fr;
        const float bvv = b0v[n];
#pragma unroll
        for (int r = 0; r < 4; ++r) {
          const int m = m0 + wm + mi * 16 + lane4 + r;
          C[(size_t)m * D + n] = acc[mi][ni][r] + bvv;
        }
      }
  }
}

// ---------------- transposed MFMA flash attention, 8-wave 2-phase ----------
// grid: 512 blocks = (S/256) x H x B via XCD-contiguous swizzle; block 512
// threads (8 waves); wave w owns Q rows [q0 + w*32, +32). Double-buffered
// Ks/Vt shared by all waves; stage(j+1) issued before compute(j); ONE
// vmcnt(0)+s_barrier per kv-tile. Per-wave compute body identical to r4-9.
__global__ __launch_bounds__(512, 4) void attn_mfma_kernel(
    const u16* __restrict__ Qb, const u16* __restrict__ Kb, const u16* __restrict__ Vtb,
    u16* __restrict__ Ohi, u16* __restrict__ Olo, int S_)
{
  __shared__ u16 Ks[2][64 * 64];   // Ks[key][dk], XOR-swizzled 16B chunks
  __shared__ u16 Vt[2][64 * 64];   // Vt[dk][key], XOR-swizzled 16B chunks
  __shared__ u16 Pl[8][32 * PSTR]; // per-wave P[q][key]

  const int tid = threadIdx.x;
  const int lane = tid & 63, w = tid >> 6;
  const int fr = lane & 15, fq = lane >> 4;

  // XCD-contiguous swizzle: 64 consecutive swizzled ids (= 8 full (b,h)
  // pairs at gqx=8) land on one XCD -> per-XCD KV footprint ~4MB = L2.
  const int gqx = gridDim.x;
  const int nwg = gqx * gridDim.y * gridDim.z;
  int id = (blockIdx.z * gridDim.y + blockIdx.y) * gqx + blockIdx.x;
  id = (id & 7) * (nwg >> 3) + (id >> 3);
  const int qx = id % gqx;
  const int rest = id / gqx;
  const int h = rest % H;
  const int b = rest / H;

  const int q0 = qx * 256;
  const int wq = w * 32;
  const size_t base = (size_t)(b * H + h) * S_ * DK;

  const int srow = tid >> 3;                 // 0..63
  const int scb = (tid & 7) ^ (srow & 7);    // swizzled 16B chunk

  // stage kv-tile at key offset j0 into buffer bufi (2 loads/thread)
  auto stage_kv = [&](int j0, int bufi) {
    __builtin_amdgcn_global_load_lds((gvoid*)(Kb + base + (size_t)(j0 + srow) * DK + scb * 8),
                                     (lvoid*)(&Ks[bufi][0] + tid * 8), 16, 0, 0);
    __builtin_amdgcn_global_load_lds((gvoid*)(Vtb + base + (size_t)srow * S_ + j0 + scb * 8),
                                     (lvoid*)(&Vt[bufi][0] + tid * 8), 16, 0, 0);
  };

  // prologue: stage tile 0; Q fragment loads ride the same vmcnt(0)
  stage_kv(0, 0);

  v8s qa[2][2];
#pragma unroll
  for (int ni = 0; ni < 2; ++ni)
#pragma unroll
    for (int ks = 0; ks < 2; ++ks)
      qa[ni][ks] = *(const v8s*)(Qb + base + (size_t)(q0 + wq + ni * 16 + fr) * DK + ks * 32 + fq * 8);

  v4f o[4][2];
  float lsum[2] = {0.f, 0.f};
#pragma unroll
  for (int mi = 0; mi < 4; ++mi)
#pragma unroll
    for (int ni = 0; ni < 2; ++ni) o[mi][ni] = (v4f){0.f, 0.f, 0.f, 0.f};

  asm volatile("s_waitcnt vmcnt(0)" ::: "memory");
  __builtin_amdgcn_s_barrier();
  cfence();

  const int NT = S_ >> 6;
  for (int jt = 0; jt < NT; ++jt) {
    const int cur = jt & 1;
    // prefetch next tile into the other buffer: safe — all waves finished
    // reading it (tile jt-1) before the barrier that ended last iteration.
    if (jt + 1 < NT) stage_kv((jt + 1) * 64, cur ^ 1);

    const u16* Kc = &Ks[cur][0];
    const u16* Vc = &Vt[cur][0];

    // ---- S^T = K . Q^T : C[key][q] ----
    v4f s[4][2];
#pragma unroll
    for (int mi = 0; mi < 4; ++mi)
#pragma unroll
      for (int ni = 0; ni < 2; ++ni) s[mi][ni] = (v4f){0.f, 0.f, 0.f, 0.f};
#pragma unroll
    for (int ks = 0; ks < 2; ++ks) {
      v8s kb[4];
#pragma unroll
      for (int mi = 0; mi < 4; ++mi) {
        const int row = mi * 16 + fr;  // key
        kb[mi] = *(const v8s*)&Kc[row * 64 + (((ks * 4 + fq) ^ (row & 7)) * 8)];
      }
#pragma unroll
      for (int mi = 0; mi < 4; ++mi)
#pragma unroll
        for (int ni = 0; ni < 2; ++ni)
          s[mi][ni] = __builtin_amdgcn_mfma_f32_16x16x32_bf16(kb[mi], qa[ni][ks], s[mi][ni], 0, 0, 0);
    }

    // ---- P = exp(S/8), packed write P[q][key] ----
#pragma unroll
    for (int mi = 0; mi < 4; ++mi)
#pragma unroll
      for (int ni = 0; ni < 2; ++ni) {
        float p[4];
#pragma unroll
        for (int r = 0; r < 4; ++r) p[r] = __expf(s[mi][ni][r] * 0.125f);
        lsum[ni] += (p[0] + p[1]) + (p[2] + p[3]);
        uint2 pk;
        pk.x = pk_bf16(p[0], p[1]);
        pk.y = pk_bf16(p[2], p[3]);
        *(uint2*)&Pl[w][(ni * 16 + fr) * PSTR + mi * 16 + fq * 4] = pk;
      }

    // ---- O^T += V^T . P^T : C[d][q] ---- (wave-private Pl, in-wave ordering)
#pragma unroll
    for (int ks = 0; ks < 2; ++ks) {
      v8s vb[4], pa[2];
#pragma unroll
      for (int mi = 0; mi < 4; ++mi) {
        const int row = mi * 16 + fr;  // d
        vb[mi] = *(const v8s*)&Vc[row * 64 + (((ks * 4 + fq) ^ (row & 7)) * 8)];
      }
#pragma unroll
      for (int ni = 0; ni < 2; ++ni)
        pa[ni] = *(const v8s*)&Pl[w][(ni * 16 + fr) * PSTR + ks * 32 + fq * 8];
#pragma unroll
      for (int mi = 0; mi < 4; ++mi)
#pragma unroll
        for (int ni = 0; ni < 2; ++ni)
          o[mi][ni] = __builtin_amdgcn_mfma_f32_16x16x32_bf16(vb[mi], pa[ni], o[mi][ni], 0, 0, 0);
    }

    // publish: stage(jt+1) complete, everyone done reading buf cur.
    asm volatile("s_waitcnt vmcnt(0)" ::: "memory");
    cfence();
    __builtin_amdgcn_s_barrier();
    cfence();
  }

  float linv[2];
#pragma unroll
  for (int ni = 0; ni < 2; ++ni) {
    float l = lsum[ni];
    l += __shfl_xor(l, 16);
    l += __shfl_xor(l, 32);
    linv[ni] = 1.f / l;
  }

#pragma unroll
  for (int ni = 0; ni < 2; ++ni) {
    const int q = q0 + wq + ni * 16 + fr;
    const size_t rowbase = (size_t)(b * S_ + q) * D + h * DK;
#pragma unroll
    for (int mi = 0; mi < 4; ++mi) {
      const int d0 = mi * 16 + fq * 4;
      float v[4];
      unsigned u[4];
      float res[4];
#pragma unroll
      for (int r = 0; r < 4; ++r) {
        v[r] = o[mi][ni][r] * linv[ni];
        u[r] = __float_as_uint(v[r]);
        res[r] = v[r] - __uint_as_float(u[r] & 0xFFFF0000u);
      }
      uint2 hi, lo;
      hi.x = (u[1] & 0xFFFF0000u) | (u[0] >> 16);
      hi.y = (u[3] & 0xFFFF0000u) | (u[2] >> 16);
      lo.x = pk_bf16(res[0], res[1]);
      lo.y = pk_bf16(res[2], res[3]);
      *(uint2*)(Ohi + rowbase + d0) = hi;
      *(uint2*)(Olo + rowbase + d0) = lo;
    }
  }
}

extern "C" void kernel_launch(void* const* d_in, const int* in_sizes, int n_in,
                              void* d_out, int out_size, void* d_ws, size_t ws_size,
                              hipStream_t stream) {
  const float* x  = (const float*)d_in[0];
  const float* Wq = (const float*)d_in[1];
  const float* bq = (const float*)d_in[2];
  const float* Wk = (const float*)d_in[3];
  const float* bk = (const float*)d_in[4];
  const float* Wv = (const float*)d_in[5];
  const float* bv = (const float*)d_in[6];
  const float* Wo = (const float*)d_in[7];
  const float* bo = (const float*)d_in[8];

  const int M = in_sizes[0] / D;  // 8192
  const int B = 4;
  const int S_ = M / B;           // 2048
  const size_t MD = (size_t)M * D;
  const size_t DD = (size_t)D * D;

  // ws (u16 units): Qb | Kb | Vtb | xs_hi | xs_lo | Ohi | Olo | wo_hi | wo_lo
  u16* Qb    = (u16*)d_ws;
  u16* Kb    = Qb + MD;
  u16* Vtb   = Kb + MD;
  u16* xs_hi = Vtb + MD;
  u16* xs_lo = xs_hi + MD;
  u16* Ohi   = xs_lo + MD;
  u16* Olo   = Ohi + MD;
  u16* wo_hi = Olo + MD;
  u16* wo_lo = wo_hi + DD;

  // concatenated QKV weight splits live in d_out (dead until final GEMM)
  u16* wqkv_hi = (u16*)d_out;
  u16* wqkv_lo = wqkv_hi + 3 * DD;

  const int n4x = (int)(MD / 4);
  const int n4w = (int)(DD / 4);
  const int nsb = (n4x + 4 * n4w + 255) / 256;
  split_all_kernel<<<nsb, 256, 0, stream>>>(x, Wq, Wk, Wv, Wo,
                                            xs_hi, xs_lo, wqkv_hi, wqkv_lo,
                                            wo_hi, wo_lo, n4x);

  dim3 gq(M / 256, 3 * D / 256);  // (32, 12) -> 384 blocks
  gemm_pipe_kernel<0><<<gq, 512, 0, stream>>>(
      xs_hi, xs_lo, wqkv_hi, wqkv_lo, bq, bk, bv, Qb, Kb, Vtb, nullptr, S_);

  dim3 ga(S_ / 256, H, B);        // (8, 16, 4) -> 512 blocks
  attn_mfma_kernel<<<ga, 512, 0, stream>>>(Qb, Kb, Vtb, Ohi, Olo, S_);

  dim3 go(M / 256, D / 256);      // (32, 4) -> 128 blocks
  gemm_pipe_kernel<1><<<go, 512, 0, stream>>>(
      Ohi, Olo, wo_hi, wo_lo, bo, nullptr, nullptr, nullptr, nullptr, nullptr,
      (float*)d_out, S_);
}

// Round 7
// 395.216 us; speedup vs baseline: 1.0805x; 1.0805x over previous
//
#include <hip/hip_runtime.h>
#include <hip/hip_bf16.h>
#include <math.h>

// MultiHeadAttention: B=4, S=2048, D=1024, H=16, DK=64, fp32 in/out.
// Round 11:
//  - GEMMs: BM=256 x BN=192 (QKV, grid 512 = 2 exact CU rounds) / BN=128
//    (out, grid 256 = 1 round). 8 waves 4m x 2n, wave 64x96 (ratio 3.6) /
//    64x64. 2 LDS buffers with fine-grained grouped staging: X={Ahi,Ball}
//    issued ph0, Y={Alo} issued ph1; waits vmcnt(2)/vmcnt(5|4) NEVER 0,
//    phase 2 needs no wait/barrier (Blo arrives with X). Fixes round-10's
//    per-chunk vmcnt(0) drain + 1.5-round grid tail. Pass order unchanged
//    (hi*hi, lo*hi, hi*lo) -> bit-identical numerics.
//  - attention + fused split unchanged from round 9.

constexpr int D = 1024;
constexpr int H = 16;
constexpr int DK = 64;
constexpr int PSTR = 72;  // P row stride (u16)

typedef unsigned short u16;
typedef __attribute__((ext_vector_type(8))) short v8s;
typedef __attribute__((ext_vector_type(4))) float v4f;
typedef const __attribute__((address_space(1))) void gvoid;
typedef __attribute__((address_space(3))) void lvoid;
typedef __attribute__((address_space(3))) u16 ls_u16;
typedef __attribute__((address_space(3))) v8s lv8s;

__device__ __forceinline__ u16 rne_bf16(float f) {
  unsigned u = __float_as_uint(f);
  u += 0x7FFFu + ((u >> 16) & 1u);
  return (u16)(u >> 16);
}

__device__ __forceinline__ unsigned pk_bf16(float a, float b) {
  __hip_bfloat162 t = __float22bfloat162_rn(float2{a, b});
  return *reinterpret_cast<unsigned*>(&t);
}

__device__ __forceinline__ void cfence() { asm volatile("" ::: "memory"); }

// ---------------- fp32 -> bf16 hi/lo split ----------------
__device__ __forceinline__ void split_body(const float* __restrict__ in,
                                           u16* __restrict__ hi, u16* __restrict__ lo,
                                           int i)
{
  const float4 v = ((const float4*)in)[i];
  const float f[4] = {v.x, v.y, v.z, v.w};
  ushort4 h, l;
  u16 hh[4], ll[4];
#pragma unroll
  for (int j = 0; j < 4; ++j) {
    const unsigned u = __float_as_uint(f[j]);
    hh[j] = (u16)(u >> 16);
    const float hf = __uint_as_float(u & 0xFFFF0000u);
    ll[j] = rne_bf16(f[j] - hf);
  }
  h.x = hh[0]; h.y = hh[1]; h.z = hh[2]; h.w = hh[3];
  l.x = ll[0]; l.y = ll[1]; l.z = ll[2]; l.w = ll[3];
  ((ushort4*)hi)[i] = h;
  ((ushort4*)lo)[i] = l;
}

// one launch for ALL splits: linear float4 index space =
// [x: n4x) ++ [Wq,Wk,Wv: 3*N4W) ++ [Wo: N4W)
__global__ __launch_bounds__(256) void split_all_kernel(
    const float* __restrict__ x,
    const float* __restrict__ w0, const float* __restrict__ w1,
    const float* __restrict__ w2, const float* __restrict__ w3,
    u16* __restrict__ xs_hi, u16* __restrict__ xs_lo,
    u16* __restrict__ qkv_hi, u16* __restrict__ qkv_lo,
    u16* __restrict__ o_hi, u16* __restrict__ o_lo, int n4x)
{
  constexpr int N4W = (int)(D * (size_t)D / 4);  // 262144 (pow2)
  const int i = blockIdx.x * 256 + threadIdx.x;
  if (i < n4x) {
    split_body(x, xs_hi, xs_lo, i);
    return;
  }
  const int t = i - n4x;
  const int y = t / N4W;        // pow2 -> shift
  const int j = t - y * N4W;
  if (y >= 4) return;
  const float* src = (y == 0) ? w0 : (y == 1) ? w1 : (y == 2) ? w2 : w3;
  const size_t off = (size_t)y * (size_t)(D * (size_t)D);
  u16* hi = (y < 3) ? qkv_hi + off : o_hi;
  u16* lo = (y < 3) ? qkv_lo + off : o_lo;
  split_body(src, hi, lo, j);
}

// ---------------- staging helpers (pre-swizzled source, linear LDS dst) ------
// LDS chunk c of row r holds global 16B-chunk c ^ ((r>>1)&3).
template<int R>
__device__ __forceinline__ void stage_arr(const u16* __restrict__ src, ls_u16* dst,
                                          int tid, int row0, int k0)
{
  const int cg = (tid & 3) ^ ((tid >> 3) & 3);
#pragma unroll
  for (int j = 0; j < R / 128; ++j) {
    const int row = j * 128 + (tid >> 2);
    __builtin_amdgcn_global_load_lds(
        (gvoid*)(src + (size_t)(row0 + row) * D + k0 + cg * 8),
        (lvoid*)(dst + j * 4096 + tid * 8), 16, 0, 0);
  }
}

// stage Bhi (BN rows) then Blo (BN rows) as one contiguous 2*BN-row array.
// j-boundaries keep the hi/lo source split per-wave-uniform; LDS dest linear.
template<int BN>
__device__ __forceinline__ void stage_b(const u16* __restrict__ hi_src,
                                        const u16* __restrict__ lo_src,
                                        ls_u16* dst, int tid, int n0, int k0)
{
  const int cg = (tid & 3) ^ ((tid >> 3) & 3);
#pragma unroll
  for (int j = 0; j < (2 * BN) / 128; ++j) {
    const int row = j * 128 + (tid >> 2);
    const u16* s = (row < BN) ? hi_src : lo_src;
    const int gr = (row < BN) ? row : row - BN;
    __builtin_amdgcn_global_load_lds(
        (gvoid*)(s + (size_t)(n0 + gr) * D + k0 + cg * 8),
        (lvoid*)(dst + j * 4096 + tid * 8), 16, 0, 0);
  }
}

// ---------------- 2-buffer counted-vmcnt split-bf16 GEMM ---------------------
// BM=256 x BN tile, 512 threads = 8 waves (4m x 2n), wave 64 x BN/2.
// Buffer = [Ahi | Alo | Bhi;Blo]. Stage groups: X={Ahi(2),Ball(2BN/128)} at
// ph0, Y={Alo(2)} at ph1. Waits: ph0 vmcnt(|Y|)=2, ph1 vmcnt(|X|), ph2 none.
// 3 MFMA passes: hi*hi, lo*hi, hi*lo (order == rounds 4-10).
// EPI=0: QKV epilogue (per-column wsel; Q/K natural bf16, V transposed).
// EPI=1: fp32 natural + bias.
template<int BN, int EPI>
__global__ __launch_bounds__(512, 2) void gemm_pipe_kernel(
    const u16* __restrict__ Ahi, const u16* __restrict__ Alo,
    const u16* __restrict__ Whi, const u16* __restrict__ Wlo,
    const float* __restrict__ b0v, const float* __restrict__ b1v, const float* __restrict__ b2v,
    u16* __restrict__ Qb, u16* __restrict__ Kb, u16* __restrict__ Vtb,
    float* __restrict__ C, int S_)
{
  constexpr int BM = 256;
  constexpr int TA = BM * 32;            // u16 per A array tile
  constexpr int TB = BN * 32;            // u16 per B array tile
  constexpr int BUFSZ = 2 * TA + 2 * TB;
  constexpr int RM = 4;
  constexpr int RN = BN / 32;            // 6 (BN=192) or 4 (BN=128)
  constexpr int XL = 2 + (2 * BN) / 128; // loads in group X (5 or 4)
  __shared__ u16 lds[2][BUFSZ];          // 112 KiB (BN=192) / 96 KiB (BN=128)

  const int tid = threadIdx.x;
  const int lane = tid & 63, w = tid >> 6;
  const int wm = (w >> 1) * 64, wn = (w & 1) * (BN / 2);
  const int fr = lane & 15, fq = lane >> 4;
  const int csw = (fq ^ ((fr >> 1) & 3)) * 8;  // swizzled k-chunk (u16 units)

  // XCD-contiguous id, then grouped mapping (GM m-tiles x all n per group).
  const int gx = gridDim.x;   // m tiles (multiple of GM)
  const int gyd = gridDim.y;  // n tiles
  const int nwg = gx * gyd;   // multiple of 8
  int id = blockIdx.y * gx + blockIdx.x;
  id = (id & 7) * (nwg >> 3) + (id >> 3);
  constexpr int GM = 4;
  const int per_grp = GM * gyd;
  const int grp = id / per_grp;
  const int ing = id - grp * per_grp;
  const int m0 = (grp * GM + (ing & (GM - 1))) * BM;
  const int n0 = (ing / GM) * BN;

  v4f acc[RM][RN];
#pragma unroll
  for (int mi = 0; mi < RM; ++mi)
#pragma unroll
    for (int ni = 0; ni < RN; ++ni) acc[mi][ni] = (v4f){0.f, 0.f, 0.f, 0.f};

  ls_u16* pb0 = (ls_u16*)&lds[0][0];
  ls_u16* pb1 = (ls_u16*)&lds[1][0];

  int aoff[RM], boff[RN];
#pragma unroll
  for (int i = 0; i < RM; ++i) aoff[i] = (wm + i * 16 + fr) * 32 + csw;
#pragma unroll
  for (int i = 0; i < RN; ++i) boff[i] = 2 * TA + (wn + i * 16 + fr) * 32 + csw;

  // prologue: X(0) then Y(0) into pb0
  stage_arr<BM>(Ahi, pb0, tid, m0, 0);
  stage_b<BN>(Whi, Wlo, pb0 + 2 * TA, tid, n0, 0);
  stage_arr<BM>(Alo, pb0 + TA, tid, m0, 0);

#pragma unroll 2
  for (int k = 0; k < 32; ++k) {
    const int ks = (k + 1 < 32) ? (k + 1) * 32 : 31 * 32;  // clamp keeps counts uniform

    // ===== phase 0: wait X(k) (leave Y(k)); read ah,bh; issue X(k+1); hi*hi =====
    asm volatile("s_waitcnt vmcnt(2)" ::: "memory");
    __builtin_amdgcn_s_barrier();
    cfence();
    v8s ah[RM], bh[RN];
#pragma unroll
    for (int i = 0; i < RM; ++i) ah[i] = *(const lv8s*)(pb0 + aoff[i]);
#pragma unroll
    for (int i = 0; i < RN; ++i) bh[i] = *(const lv8s*)(pb0 + boff[i]);
    stage_arr<BM>(Ahi, pb1, tid, m0, ks);
    stage_b<BN>(Whi, Wlo, pb1 + 2 * TA, tid, n0, ks);
    __builtin_amdgcn_s_setprio(1);
#pragma unroll
    for (int mi = 0; mi < RM; ++mi)
#pragma unroll
      for (int ni = 0; ni < RN; ++ni)
        acc[mi][ni] = __builtin_amdgcn_mfma_f32_16x16x32_bf16(ah[mi], bh[ni], acc[mi][ni], 0, 0, 0);
    __builtin_amdgcn_s_setprio(0);
    cfence();

    // ===== phase 1: wait Y(k) (leave X(k+1)); read Alo; issue Y(k+1); lo*hi =====
    if constexpr (XL == 5) {
      asm volatile("s_waitcnt vmcnt(5)" ::: "memory");
    } else {
      asm volatile("s_waitcnt vmcnt(4)" ::: "memory");
    }
    __builtin_amdgcn_s_barrier();
    cfence();
    v8s ta[RM];
#pragma unroll
    for (int i = 0; i < RM; ++i) ta[i] = *(const lv8s*)(pb0 + TA + aoff[i]);
    stage_arr<BM>(Alo, pb1 + TA, tid, m0, ks);
    __builtin_amdgcn_s_setprio(1);
#pragma unroll
    for (int mi = 0; mi < RM; ++mi)
#pragma unroll
      for (int ni = 0; ni < RN; ++ni)
        acc[mi][ni] = __builtin_amdgcn_mfma_f32_16x16x32_bf16(ta[mi], bh[ni], acc[mi][ni], 0, 0, 0);
    __builtin_amdgcn_s_setprio(0);
    cfence();

    // ===== phase 2: no wait/barrier (Blo(k) arrived with X(k)); hi*lo =====
    v8s tb[RN];
#pragma unroll
    for (int i = 0; i < RN; ++i) tb[i] = *(const lv8s*)(pb0 + boff[i] + TB);
    __builtin_amdgcn_s_setprio(1);
#pragma unroll
    for (int mi = 0; mi < RM; ++mi)
#pragma unroll
      for (int ni = 0; ni < RN; ++ni)
        acc[mi][ni] = __builtin_amdgcn_mfma_f32_16x16x32_bf16(ah[mi], tb[ni], acc[mi][ni], 0, 0, 0);
    __builtin_amdgcn_s_setprio(0);
    cfence();

    ls_u16* t = pb0; pb0 = pb1; pb1 = t;
  }

  const int lane4 = fq * 4;
  if constexpr (EPI == 0) {
    const int bb = m0 / S_;     // block spans a single batch (S_ % BM == 0)
    const int s0 = m0 - bb * S_;
#pragma unroll
    for (int mi = 0; mi < RM; ++mi) {
#pragma unroll
      for (int ni = 0; ni < RN; ++ni) {
        const int n = n0 + wn + ni * 16 + fr;
        const int wsel = n >> 10;          // uniform within a 16-col group
        const float* bias = (wsel == 0) ? b0v : (wsel == 1) ? b1v : b2v;
        u16* Cb = (wsel == 0) ? Qb : (wsel == 1) ? Kb : Vtb;
        const int nl = n & (D - 1);
        const float bvv = bias[nl];
        const int h = nl >> 6, dk = nl & 63;
#pragma unroll
        for (int r = 0; r < 4; ++r) {
          const int s = s0 + wm + mi * 16 + lane4 + r;
          const float val = acc[mi][ni][r] + bvv;
          if (wsel < 2)
            Cb[((size_t)(bb * H + h) * S_ + s) * DK + dk] = rne_bf16(val);
          else
            Cb[((size_t)(bb * H + h) * DK + dk) * S_ + s] = rne_bf16(val);
        }
      }
    }
  } else {
#pragma unroll
    for (int mi = 0; mi < RM; ++mi)
#pragma unroll
      for (int ni = 0; ni < RN; ++ni) {
        const int n = n0 + wn + ni * 16 + fr;
        const float bvv = b0v[n];
#pragma unroll
        for (int r = 0; r < 4; ++r) {
          const int m = m0 + wm + mi * 16 + lane4 + r;
          C[(size_t)m * D + n] = acc[mi][ni][r] + bvv;
        }
      }
  }
}

// ---------------- transposed MFMA flash attention, 8-wave 2-phase ----------
// grid: 512 blocks = (S/256) x H x B via XCD-contiguous swizzle; block 512
// threads (8 waves); wave w owns Q rows [q0 + w*32, +32). Double-buffered
// Ks/Vt shared by all waves; stage(j+1) issued before compute(j); ONE
// vmcnt(0)+s_barrier per kv-tile. Per-wave compute body identical to r4-10.
__global__ __launch_bounds__(512, 4) void attn_mfma_kernel(
    const u16* __restrict__ Qb, const u16* __restrict__ Kb, const u16* __restrict__ Vtb,
    u16* __restrict__ Ohi, u16* __restrict__ Olo, int S_)
{
  __shared__ u16 Ks[2][64 * 64];   // Ks[key][dk], XOR-swizzled 16B chunks
  __shared__ u16 Vt[2][64 * 64];   // Vt[dk][key], XOR-swizzled 16B chunks
  __shared__ u16 Pl[8][32 * PSTR]; // per-wave P[q][key]

  const int tid = threadIdx.x;
  const int lane = tid & 63, w = tid >> 6;
  const int fr = lane & 15, fq = lane >> 4;

  // XCD-contiguous swizzle: 64 consecutive swizzled ids (= 8 full (b,h)
  // pairs at gqx=8) land on one XCD -> per-XCD KV footprint ~4MB = L2.
  const int gqx = gridDim.x;
  const int nwg = gqx * gridDim.y * gridDim.z;
  int id = (blockIdx.z * gridDim.y + blockIdx.y) * gqx + blockIdx.x;
  id = (id & 7) * (nwg >> 3) + (id >> 3);
  const int qx = id % gqx;
  const int rest = id / gqx;
  const int h = rest % H;
  const int b = rest / H;

  const int q0 = qx * 256;
  const int wq = w * 32;
  const size_t base = (size_t)(b * H + h) * S_ * DK;

  const int srow = tid >> 3;                 // 0..63
  const int scb = (tid & 7) ^ (srow & 7);    // swizzled 16B chunk

  // stage kv-tile at key offset j0 into buffer bufi (2 loads/thread)
  auto stage_kv = [&](int j0, int bufi) {
    __builtin_amdgcn_global_load_lds((gvoid*)(Kb + base + (size_t)(j0 + srow) * DK + scb * 8),
                                     (lvoid*)(&Ks[bufi][0] + tid * 8), 16, 0, 0);
    __builtin_amdgcn_global_load_lds((gvoid*)(Vtb + base + (size_t)srow * S_ + j0 + scb * 8),
                                     (lvoid*)(&Vt[bufi][0] + tid * 8), 16, 0, 0);
  };

  // prologue: stage tile 0; Q fragment loads ride the same vmcnt(0)
  stage_kv(0, 0);

  v8s qa[2][2];
#pragma unroll
  for (int ni = 0; ni < 2; ++ni)
#pragma unroll
    for (int ks = 0; ks < 2; ++ks)
      qa[ni][ks] = *(const v8s*)(Qb + base + (size_t)(q0 + wq + ni * 16 + fr) * DK + ks * 32 + fq * 8);

  v4f o[4][2];
  float lsum[2] = {0.f, 0.f};
#pragma unroll
  for (int mi = 0; mi < 4; ++mi)
#pragma unroll
    for (int ni = 0; ni < 2; ++ni) o[mi][ni] = (v4f){0.f, 0.f, 0.f, 0.f};

  asm volatile("s_waitcnt vmcnt(0)" ::: "memory");
  __builtin_amdgcn_s_barrier();
  cfence();

  const int NT = S_ >> 6;
  for (int jt = 0; jt < NT; ++jt) {
    const int cur = jt & 1;
    // prefetch next tile into the other buffer: safe — all waves finished
    // reading it (tile jt-1) before the barrier that ended last iteration.
    if (jt + 1 < NT) stage_kv((jt + 1) * 64, cur ^ 1);

    const u16* Kc = &Ks[cur][0];
    const u16* Vc = &Vt[cur][0];

    // ---- S^T = K . Q^T : C[key][q] ----
    v4f s[4][2];
#pragma unroll
    for (int mi = 0; mi < 4; ++mi)
#pragma unroll
      for (int ni = 0; ni < 2; ++ni) s[mi][ni] = (v4f){0.f, 0.f, 0.f, 0.f};
#pragma unroll
    for (int ks = 0; ks < 2; ++ks) {
      v8s kb[4];
#pragma unroll
      for (int mi = 0; mi < 4; ++mi) {
        const int row = mi * 16 + fr;  // key
        kb[mi] = *(const v8s*)&Kc[row * 64 + (((ks * 4 + fq) ^ (row & 7)) * 8)];
      }
#pragma unroll
      for (int mi = 0; mi < 4; ++mi)
#pragma unroll
        for (int ni = 0; ni < 2; ++ni)
          s[mi][ni] = __builtin_amdgcn_mfma_f32_16x16x32_bf16(kb[mi], qa[ni][ks], s[mi][ni], 0, 0, 0);
    }

    // ---- P = exp(S/8), packed write P[q][key] ----
#pragma unroll
    for (int mi = 0; mi < 4; ++mi)
#pragma unroll
      for (int ni = 0; ni < 2; ++ni) {
        float p[4];
#pragma unroll
        for (int r = 0; r < 4; ++r) p[r] = __expf(s[mi][ni][r] * 0.125f);
        lsum[ni] += (p[0] + p[1]) + (p[2] + p[3]);
        uint2 pk;
        pk.x = pk_bf16(p[0], p[1]);
        pk.y = pk_bf16(p[2], p[3]);
        *(uint2*)&Pl[w][(ni * 16 + fr) * PSTR + mi * 16 + fq * 4] = pk;
      }

    // ---- O^T += V^T . P^T : C[d][q] ---- (wave-private Pl, in-wave ordering)
#pragma unroll
    for (int ks = 0; ks < 2; ++ks) {
      v8s vb[4], pa[2];
#pragma unroll
      for (int mi = 0; mi < 4; ++mi) {
        const int row = mi * 16 + fr;  // d
        vb[mi] = *(const v8s*)&Vc[row * 64 + (((ks * 4 + fq) ^ (row & 7)) * 8)];
      }
#pragma unroll
      for (int ni = 0; ni < 2; ++ni)
        pa[ni] = *(const v8s*)&Pl[w][(ni * 16 + fr) * PSTR + ks * 32 + fq * 8];
#pragma unroll
      for (int mi = 0; mi < 4; ++mi)
#pragma unroll
        for (int ni = 0; ni < 2; ++ni)
          o[mi][ni] = __builtin_amdgcn_mfma_f32_16x16x32_bf16(vb[mi], pa[ni], o[mi][ni], 0, 0, 0);
    }

    // publish: stage(jt+1) complete, everyone done reading buf cur.
    asm volatile("s_waitcnt vmcnt(0)" ::: "memory");
    cfence();
    __builtin_amdgcn_s_barrier();
    cfence();
  }

  float linv[2];
#pragma unroll
  for (int ni = 0; ni < 2; ++ni) {
    float l = lsum[ni];
    l += __shfl_xor(l, 16);
    l += __shfl_xor(l, 32);
    linv[ni] = 1.f / l;
  }

#pragma unroll
  for (int ni = 0; ni < 2; ++ni) {
    const int q = q0 + wq + ni * 16 + fr;
    const size_t rowbase = (size_t)(b * S_ + q) * D + h * DK;
#pragma unroll
    for (int mi = 0; mi < 4; ++mi) {
      const int d0 = mi * 16 + fq * 4;
      float v[4];
      unsigned u[4];
      float res[4];
#pragma unroll
      for (int r = 0; r < 4; ++r) {
        v[r] = o[mi][ni][r] * linv[ni];
        u[r] = __float_as_uint(v[r]);
        res[r] = v[r] - __uint_as_float(u[r] & 0xFFFF0000u);
      }
      uint2 hi, lo;
      hi.x = (u[1] & 0xFFFF0000u) | (u[0] >> 16);
      hi.y = (u[3] & 0xFFFF0000u) | (u[2] >> 16);
      lo.x = pk_bf16(res[0], res[1]);
      lo.y = pk_bf16(res[2], res[3]);
      *(uint2*)(Ohi + rowbase + d0) = hi;
      *(uint2*)(Olo + rowbase + d0) = lo;
    }
  }
}

extern "C" void kernel_launch(void* const* d_in, const int* in_sizes, int n_in,
                              void* d_out, int out_size, void* d_ws, size_t ws_size,
                              hipStream_t stream) {
  const float* x  = (const float*)d_in[0];
  const float* Wq = (const float*)d_in[1];
  const float* bq = (const float*)d_in[2];
  const float* Wk = (const float*)d_in[3];
  const float* bk = (const float*)d_in[4];
  const float* Wv = (const float*)d_in[5];
  const float* bv = (const float*)d_in[6];
  const float* Wo = (const float*)d_in[7];
  const float* bo = (const float*)d_in[8];

  const int M = in_sizes[0] / D;  // 8192
  const int B = 4;
  const int S_ = M / B;           // 2048
  const size_t MD = (size_t)M * D;
  const size_t DD = (size_t)D * D;

  // ws (u16 units): Qb | Kb | Vtb | xs_hi | xs_lo | Ohi | Olo | wo_hi | wo_lo
  u16* Qb    = (u16*)d_ws;
  u16* Kb    = Qb + MD;
  u16* Vtb   = Kb + MD;
  u16* xs_hi = Vtb + MD;
  u16* xs_lo = xs_hi + MD;
  u16* Ohi   = xs_lo + MD;
  u16* Olo   = Ohi + MD;
  u16* wo_hi = Olo + MD;
  u16* wo_lo = wo_hi + DD;

  // concatenated QKV weight splits live in d_out (dead until final GEMM)
  u16* wqkv_hi = (u16*)d_out;
  u16* wqkv_lo = wqkv_hi + 3 * DD;

  const int n4x = (int)(MD / 4);
  const int n4w = (int)(DD / 4);
  const int nsb = (n4x + 4 * n4w + 255) / 256;
  split_all_kernel<<<nsb, 256, 0, stream>>>(x, Wq, Wk, Wv, Wo,
                                            xs_hi, xs_lo, wqkv_hi, wqkv_lo,
                                            wo_hi, wo_lo, n4x);

  dim3 gq(M / 256, 3 * D / 192);  // (32, 16) -> 512 blocks = 2 exact rounds
  gemm_pipe_kernel<192, 0><<<gq, 512, 0, stream>>>(
      xs_hi, xs_lo, wqkv_hi, wqkv_lo, bq, bk, bv, Qb, Kb, Vtb, nullptr, S_);

  dim3 ga(S_ / 256, H, B);        // (8, 16, 4) -> 512 blocks
  attn_mfma_kernel<<<ga, 512, 0, stream>>>(Qb, Kb, Vtb, Ohi, Olo, S_);

  dim3 go(M / 256, D / 128);      // (32, 8) -> 256 blocks = 1 exact round
  gemm_pipe_kernel<128, 1><<<go, 512, 0, stream>>>(
      Ohi, Olo, wo_hi, wo_lo, bo, nullptr, nullptr, nullptr, nullptr, nullptr,
      (float*)d_out, S_);
}